// Round 3
// baseline (14161.542 us; speedup 1.0000x reference)
//
#include <hip/hip_runtime.h>

// WindowedMultiHeadAttention. B=16, 56x56 tokens, C=768, 8 heads x d=96,
// 14x14 windows -> 256 windows x 196 tokens.
// Round 2: dual-dtype (device-side detect fp32 vs bf16 inputs) + ws cut to
// 154 MB (K,V materialized; Q computed on the fly in the attention kernel;
// attention output overwrites V in place).
//   detect: scan w_qkv shorts; bf16 weights have exp<=124, fp32 mantissa
//           halves hit exp>=140 with ~45%/short probability -> flag.
//   K1<FP32>: kv = win_part(x) @ w_qkv[k,v cols] + bias -> kb, vb (bf16)
//   K2<FP32>: per-(window,head): q-tile GEMM (196x96) + softmax attention
//             (softmax FIRST, then /sqrt(768)); out overwrites V slice
//   K3<FP32>: proj GEMM + bias + window reverse + residual
// ws: kb 77,070,336 B | vb/attn_out 77,070,336 B | flag 4 B  (154,140,676 B)

#define NWIN 256
#define NTOK 196
#define CDIM 768
#define NHEAD 8
#define DHEAD 96
#define C3 2304

typedef unsigned short u16;
typedef unsigned int u32;

__device__ __forceinline__ float bf2f(u16 u) {
    union { u32 i; float f; } cv;
    cv.i = ((u32)u) << 16;
    return cv.f;
}
__device__ __forceinline__ float2 bfp2f(u32 u) {
    union { u32 i; float f; } lo, hi;
    lo.i = u << 16;
    hi.i = u & 0xFFFF0000u;
    float2 r; r.x = lo.f; r.y = hi.f;
    return r;
}
__device__ __forceinline__ u16 f2bf(float f) {
    union { float f; u32 i; } cv;
    cv.f = f;
    u32 x = cv.i;
    x = x + 0x7FFFu + ((x >> 16) & 1u);   // RNE
    return (u16)(x >> 16);
}

// ------------------------------------------------------------- dtype detect
// flag=1 -> inputs are fp32; flag=0 -> bf16.
__global__ void detect_kernel(const u16* __restrict__ w, int* __restrict__ flag) {
    __shared__ int any;
    int t = threadIdx.x;
    if (t == 0) any = 0;
    __syncthreads();
    int hit = 0;
    for (int i = 0; i < 16; ++i) {
        u16 u = w[t * 16 + i];
        int e = (u >> 7) & 0xFF;
        if (e >= 140) hit = 1;    // |val| >= 2^13: impossible for bf16 weights
    }
    if (hit) atomicOr(&any, 1);
    __syncthreads();
    if (t == 0) flag[0] = any;
}

// ---------------------------------------------------------------- K1: KV GEMM
// rows = 50176 window-partitioned, cols = 1536 (k,v only), K = 768.
// Thread: 4 rows x {k[dd],v[dd],k[dd+1],v[dd+1]} (dd even).
// 384 col-groups/row = 6 waves exactly -> x broadcast, w coalesced-ish.
template<bool FP32>
__global__ __launch_bounds__(256) void kv_kernel(
    const void* __restrict__ xv, const void* __restrict__ wv,
    const void* __restrict__ bvv, const int* __restrict__ flag,
    u16* __restrict__ kb, u16* __restrict__ vb)
{
    if (flag[0] != (FP32 ? 1 : 0)) return;
    unsigned g = blockIdx.x * 256u + threadIdx.x;
    unsigned cg = g % 384u;
    unsigned rg = g / 384u;               // 0..12543
    int h  = (int)(cg / 48u);
    int dd = (int)(cg % 48u) * 2;
    int je = h * 288 + 3 * dd;            // even; use cols je+1,je+2,je+4,je+5
    int wi = (int)(rg / 49u);
    int tokbase = (int)(rg % 49u) * 4;
    int b = wi >> 4, wrem = wi & 15, wr = wrem >> 2, wc = wrem & 3;

    size_t xr[4];
#pragma unroll
    for (int rr = 0; rr < 4; ++rr) {
        int tok = tokbase + rr;
        int r = tok / 14, c = tok - r * 14;
        size_t nidx = (size_t)b * 3136 + (size_t)((wr * 14 + r) * 56 + wc * 14 + c);
        xr[rr] = nidx * CDIM;
    }

    float acc[4][4];
    {
        float b1, b2, b4, b5;
        if (FP32) {
            const float* bp = (const float*)bvv + je;
            b1 = bp[1]; b2 = bp[2]; b4 = bp[4]; b5 = bp[5];
        } else {
            const u16* bp = (const u16*)bvv + je;
            b1 = bf2f(bp[1]); b2 = bf2f(bp[2]); b4 = bf2f(bp[4]); b5 = bf2f(bp[5]);
        }
#pragma unroll
        for (int rr = 0; rr < 4; ++rr) {
            acc[rr][0] = b1; acc[rr][1] = b2; acc[rr][2] = b4; acc[rr][3] = b5;
        }
    }

    for (int k = 0; k < CDIM; k += 2) {
        float alo[4], ahi[4];
#pragma unroll
        for (int rr = 0; rr < 4; ++rr) {
            if (FP32) {
                float2 f = *(const float2*)((const float*)xv + xr[rr] + k);
                alo[rr] = f.x; ahi[rr] = f.y;
            } else {
                float2 f = bfp2f(*(const u32*)((const u16*)xv + xr[rr] + k));
                alo[rr] = f.x; ahi[rr] = f.y;
            }
        }
        float wk0[4], wk1[4];
        if (FP32) {
            const float* wp0 = (const float*)wv + (size_t)k * C3 + je;
            const float* wp1 = wp0 + C3;
            float2 f0 = *(const float2*)(wp0), f1 = *(const float2*)(wp0 + 2), f2 = *(const float2*)(wp0 + 4);
            wk0[0] = f0.y; wk0[1] = f1.x; wk0[2] = f2.x; wk0[3] = f2.y;
            float2 g0 = *(const float2*)(wp1), g1 = *(const float2*)(wp1 + 2), g2 = *(const float2*)(wp1 + 4);
            wk1[0] = g0.y; wk1[1] = g1.x; wk1[2] = g2.x; wk1[3] = g2.y;
        } else {
            const u16* wp0 = (const u16*)wv + (size_t)k * C3 + je;
            const u16* wp1 = wp0 + C3;
            float2 f0 = bfp2f(*(const u32*)(wp0));
            float2 f1 = bfp2f(*(const u32*)(wp0 + 2));
            float2 f2 = bfp2f(*(const u32*)(wp0 + 4));
            wk0[0] = f0.y; wk0[1] = f1.x; wk0[2] = f2.x; wk0[3] = f2.y;
            float2 g0 = bfp2f(*(const u32*)(wp1));
            float2 g1 = bfp2f(*(const u32*)(wp1 + 2));
            float2 g2 = bfp2f(*(const u32*)(wp1 + 4));
            wk1[0] = g0.y; wk1[1] = g1.x; wk1[2] = g2.x; wk1[3] = g2.y;
        }
#pragma unroll
        for (int rr = 0; rr < 4; ++rr)
#pragma unroll
            for (int jj = 0; jj < 4; ++jj)
                acc[rr][jj] = fmaf(alo[rr], wk0[jj],
                               fmaf(ahi[rr], wk1[jj], acc[rr][jj]));
    }

#pragma unroll
    for (int rr = 0; rr < 4; ++rr) {
        int tok = tokbase + rr;
        size_t base = ((size_t)(wi * NHEAD + h) * NTOK + tok) * DHEAD;
        u32 ku = (u32)f2bf(acc[rr][0]) | ((u32)f2bf(acc[rr][2]) << 16);
        u32 vu = (u32)f2bf(acc[rr][1]) | ((u32)f2bf(acc[rr][3]) << 16);
        *(u32*)(kb + base + dd) = ku;
        *(u32*)(vb + base + dd) = vu;
    }
}

// ------------------------------------------------- K2: q-tile GEMM + attention
// block = (window, head); thread t = query row t (t<196 active).
// Phase A: q[96] = x_window(row t) @ Wq_h + bias (LDS-staged tiles).
// Phase B: two-pass softmax attention vs global K,V (bf16), 49-key LDS chunks.
// Output overwrites this block's own V slice.
__device__ __forceinline__ float dot96(const u32* qpk, const float* kr) {
    float e = 0.f;
#pragma unroll
    for (int dp = 0; dp < 48; ++dp) {
        float2 qf = bfp2f(qpk[dp]);
        e = fmaf(qf.x, kr[2 * dp], e);
        e = fmaf(qf.y, kr[2 * dp + 1], e);
    }
    return e;
}

template<bool FP32>
__global__ __launch_bounds__(256) void qattn_kernel(
    const void* __restrict__ xv, const void* __restrict__ wv,
    const void* __restrict__ bvv, const int* __restrict__ flag,
    const u16* __restrict__ kb, u16* __restrict__ vb)
{
    if (flag[0] != (FP32 ? 1 : 0)) return;
    __shared__ float swq[32 * 96];        // 12,288 B  (Wq tile, fp32)
    __shared__ u32   sxq[196][17];        // 13,328 B  (x tile, packed bf16)
    __shared__ float sk[49 * DHEAD];      // 18,816 B
    __shared__ float sv[49 * DHEAD];      // 18,816 B   total 63,248 B

    int bh = blockIdx.x;                  // wi*8 + h
    int wi = bh >> 3;
    int h  = bh & 7;
    int t  = threadIdx.x;
    int rt = t < NTOK ? t : (NTOK - 1);

    int b = wi >> 4, wrem = wi & 15, wr = wrem >> 2, wc = wrem & 3;
    size_t xrowbase = (size_t)b * 3136 + (size_t)(wr * 14 * 56 + wc * 14);

    // ---------------- Phase A: q row for this thread ----------------
    float q[DHEAD];
#pragma unroll
    for (int d = 0; d < DHEAD; ++d) q[d] = 0.f;

#pragma unroll 1
    for (int k0 = 0; k0 < CDIM; k0 += 32) {
        // stage Wq tile: swq[kk][d] = w[(k0+kk)*2304 + h*288 + 3d]
#pragma unroll 1
        for (int i = t; i < 32 * 96; i += 256) {
            int kk = i / 96, d = i - kk * 96;
            size_t idx = (size_t)(k0 + kk) * C3 + (size_t)(h * 288 + 3 * d);
            swq[i] = FP32 ? ((const float*)wv)[idx] : bf2f(((const u16*)wv)[idx]);
        }
        // stage x tile: sxq[tok][p] = packed bf16 pair (k0+2p, k0+2p+1)
#pragma unroll 1
        for (int i = t; i < 196 * 16; i += 256) {
            int tok = i >> 4, p = i & 15;
            int r = tok / 14, c = tok - r * 14;
            size_t e0 = (xrowbase + (size_t)(r * 56 + c)) * CDIM + (size_t)(k0 + 2 * p);
            u32 u;
            if (FP32) {
                float2 f = *(const float2*)((const float*)xv + e0);
                u = (u32)f2bf(f.x) | ((u32)f2bf(f.y) << 16);
            } else {
                u = *(const u32*)((const u16*)xv + e0);
            }
            sxq[tok][p] = u;
        }
        __syncthreads();
#pragma unroll 2
        for (int kk = 0; kk < 32; ++kk) {
            float2 xp = bfp2f(sxq[rt][kk >> 1]);
            float xs = (kk & 1) ? xp.y : xp.x;
            const float* wrow = &swq[kk * 96];
#pragma unroll
            for (int d = 0; d < DHEAD; ++d) q[d] = fmaf(xs, wrow[d], q[d]);
        }
        __syncthreads();
    }

    // bias + pack q to bf16 pairs
    u32 qpk[48];
#pragma unroll
    for (int dp = 0; dp < 48; ++dp) {
        int d0 = 2 * dp;
        float b0, b1;
        if (FP32) {
            b0 = ((const float*)bvv)[h * 288 + 3 * d0];
            b1 = ((const float*)bvv)[h * 288 + 3 * (d0 + 1)];
        } else {
            b0 = bf2f(((const u16*)bvv)[h * 288 + 3 * d0]);
            b1 = bf2f(((const u16*)bvv)[h * 288 + 3 * (d0 + 1)]);
        }
        qpk[dp] = (u32)f2bf(q[d0] + b0) | ((u32)f2bf(q[d0 + 1] + b1) << 16);
    }

    // ---------------- Phase B: attention ----------------
    const u16* kbase = kb + (size_t)bh * NTOK * DHEAD;
    u16*       vbase = vb + (size_t)bh * NTOK * DHEAD;

    float m = -1e30f;
#pragma unroll 1
    for (int c0 = 0; c0 < NTOK; c0 += 49) {
        const u16* kc = kbase + (size_t)c0 * DHEAD;
#pragma unroll 1
        for (int i = t; i < 49 * DHEAD; i += 256) sk[i] = bf2f(kc[i]);
        __syncthreads();
#pragma unroll 1
        for (int kk = 0; kk < 49; ++kk) {
            float e = dot96(qpk, &sk[kk * DHEAD]);
            m = fmaxf(m, e);
        }
        __syncthreads();
    }

    float l = 0.f;
    float acc[DHEAD];
#pragma unroll
    for (int d = 0; d < DHEAD; ++d) acc[d] = 0.f;

#pragma unroll 1
    for (int c0 = 0; c0 < NTOK; c0 += 49) {
        const u16* kc = kbase + (size_t)c0 * DHEAD;
        const u16* vc = vbase + (size_t)c0 * DHEAD;
#pragma unroll 1
        for (int i = t; i < 49 * DHEAD; i += 256) {
            sk[i] = bf2f(kc[i]);
            sv[i] = bf2f(vc[i]);
        }
        __syncthreads();
#pragma unroll 1
        for (int kk = 0; kk < 49; ++kk) {
            float e = dot96(qpk, &sk[kk * DHEAD]);
            float wgt = __expf(e - m);
            l += wgt;
            const float* vr = &sv[kk * DHEAD];
#pragma unroll
            for (int d = 0; d < DHEAD; ++d) acc[d] = fmaf(wgt, vr[d], acc[d]);
        }
        __syncthreads();
    }

    if (t < NTOK) {
        float scale = 1.0f / (l * 27.712812921102035f);  // softmax, THEN /sqrt(768)
        u16* orow = vbase + (size_t)t * DHEAD;           // in-place over own V slice
#pragma unroll
        for (int dp = 0; dp < 48; ++dp) {
            u32 lo = f2bf(acc[2 * dp] * scale);
            u32 hi = f2bf(acc[2 * dp + 1] * scale);
            ((u32*)orow)[dp] = lo | (hi << 16);
        }
    }
}

// --------------------------------------------- K3: proj + reverse + residual
template<bool FP32>
__global__ __launch_bounds__(256) void proj_kernel(
    const u16* __restrict__ ao,            // (256*8,196,96) attn out (was V)
    const void* __restrict__ wpv, const void* __restrict__ bpv,
    const void* __restrict__ xv, const int* __restrict__ flag,
    void* __restrict__ outv)
{
    if (flag[0] != (FP32 ? 1 : 0)) return;
    unsigned g = blockIdx.x * 256u + threadIdx.x;
    unsigned cg = g % 192u;
    unsigned rg = g / 192u;               // 0..12543
    int col4 = (int)cg * 4;
    int rowbase = (int)rg * 4;

    size_t abase[4];
#pragma unroll
    for (int rr = 0; rr < 4; ++rr) {
        int row = rowbase + rr;
        int b = row / 3136;
        int n = row - b * 3136;
        int gr = n / 56, gc = n - gr * 56;
        int wr = gr / 14, wro = gr - wr * 14;
        int wc = gc / 14, wco = gc - wc * 14;
        int wi = b * 16 + wr * 4 + wc;
        int tok = wro * 14 + wco;
        abase[rr] = ((size_t)(wi * NHEAD) * NTOK + tok) * (size_t)DHEAD;
    }

    float acc[4][4];
#pragma unroll
    for (int jj = 0; jj < 4; ++jj) {
        float bvj = FP32 ? ((const float*)bpv)[col4 + jj]
                         : bf2f(((const u16*)bpv)[col4 + jj]);
#pragma unroll
        for (int rr = 0; rr < 4; ++rr) acc[rr][jj] = bvj;
    }

#pragma unroll 1
    for (int h = 0; h < NHEAD; ++h) {
        const u16* a0 = ao + abase[0] + (size_t)h * (NTOK * DHEAD);
        const u16* a1 = ao + abase[1] + (size_t)h * (NTOK * DHEAD);
        const u16* a2 = ao + abase[2] + (size_t)h * (NTOK * DHEAD);
        const u16* a3 = ao + abase[3] + (size_t)h * (NTOK * DHEAD);
        for (int k = 0; k < DHEAD; k += 2) {
            float2 v0 = bfp2f(*(const u32*)(a0 + k));
            float2 v1 = bfp2f(*(const u32*)(a1 + k));
            float2 v2 = bfp2f(*(const u32*)(a2 + k));
            float2 v3 = bfp2f(*(const u32*)(a3 + k));
            float wk0[4], wk1[4];
            if (FP32) {
                const float* wc0 = (const float*)wpv + (size_t)(h * DHEAD + k) * CDIM + col4;
                float4 w0 = *(const float4*)(wc0);
                float4 w1 = *(const float4*)(wc0 + CDIM);
                wk0[0] = w0.x; wk0[1] = w0.y; wk0[2] = w0.z; wk0[3] = w0.w;
                wk1[0] = w1.x; wk1[1] = w1.y; wk1[2] = w1.z; wk1[3] = w1.w;
            } else {
                const u16* wc0 = (const u16*)wpv + (size_t)(h * DHEAD + k) * CDIM + col4;
                uint2 w0 = *(const uint2*)(wc0);
                uint2 w1 = *(const uint2*)(wc0 + CDIM);
                float2 w0a = bfp2f(w0.x), w0b = bfp2f(w0.y);
                float2 w1a = bfp2f(w1.x), w1b = bfp2f(w1.y);
                wk0[0] = w0a.x; wk0[1] = w0a.y; wk0[2] = w0b.x; wk0[3] = w0b.y;
                wk1[0] = w1a.x; wk1[1] = w1a.y; wk1[2] = w1b.x; wk1[3] = w1b.y;
            }
            float alo[4] = {v0.x, v1.x, v2.x, v3.x};
            float ahi[4] = {v0.y, v1.y, v2.y, v3.y};
#pragma unroll
            for (int rr = 0; rr < 4; ++rr)
#pragma unroll
                for (int jj = 0; jj < 4; ++jj)
                    acc[rr][jj] = fmaf(alo[rr], wk0[jj],
                                   fmaf(ahi[rr], wk1[jj], acc[rr][jj]));
        }
    }

#pragma unroll
    for (int rr = 0; rr < 4; ++rr) {
        int row = rowbase + rr;
        size_t off = (size_t)row * CDIM + col4;
        if (FP32) {
            float4 xf = *(const float4*)((const float*)xv + off);
            float4 o;
            o.x = acc[rr][0] + xf.x; o.y = acc[rr][1] + xf.y;
            o.z = acc[rr][2] + xf.z; o.w = acc[rr][3] + xf.w;
            *(float4*)((float*)outv + off) = o;
        } else {
            uint2 xu = *(const uint2*)((const u16*)xv + off);
            float2 xa = bfp2f(xu.x), xb = bfp2f(xu.y);
            u32 o0 = f2bf(acc[rr][0] + xa.x);
            u32 o1 = f2bf(acc[rr][1] + xa.y);
            u32 o2 = f2bf(acc[rr][2] + xb.x);
            u32 o3 = f2bf(acc[rr][3] + xb.y);
            uint2 pk;
            pk.x = o0 | (o1 << 16);
            pk.y = o2 | (o3 << 16);
            *(uint2*)((u16*)outv + off) = pk;
        }
    }
}

extern "C" void kernel_launch(void* const* d_in, const int* in_sizes, int n_in,
                              void* d_out, int out_size, void* d_ws, size_t ws_size,
                              hipStream_t stream) {
    const void* x      = d_in[0];
    const void* w_qkv  = d_in[1];
    const void* b_qkv  = d_in[2];
    const void* w_proj = d_in[3];
    const void* b_proj = d_in[4];

    const size_t per = (size_t)NWIN * NHEAD * NTOK * DHEAD;  // 38,535,168 elems
    u16* kb = (u16*)d_ws;
    u16* vb = kb + per;                                      // after K2: attn out
    int* flag = (int*)((char*)d_ws + 2 * per * sizeof(u16)); // offset 154,140,672

    detect_kernel<<<1, 256, 0, stream>>>((const u16*)w_qkv, flag);

    kv_kernel<false><<<18816, 256, 0, stream>>>(x, w_qkv, b_qkv, flag, kb, vb);
    kv_kernel<true ><<<18816, 256, 0, stream>>>(x, w_qkv, b_qkv, flag, kb, vb);

    qattn_kernel<false><<<NWIN * NHEAD, 256, 0, stream>>>(x, w_qkv, b_qkv, flag, kb, vb);
    qattn_kernel<true ><<<NWIN * NHEAD, 256, 0, stream>>>(x, w_qkv, b_qkv, flag, kb, vb);

    proj_kernel<false><<<9408, 256, 0, stream>>>(vb, w_proj, b_proj, x, flag, d_out);
    proj_kernel<true ><<<9408, 256, 0, stream>>>(vb, w_proj, b_proj, x, flag, d_out);
}